// Round 18
// baseline (2429.533 us; speedup 1.0000x reference)
//
#include <hip/hip_runtime.h>
#include <math.h>

#define L 64
#define D 38
#define HD 19
#define NL 6
#define KD 8
#define QKV 114

__device__ __forceinline__ float dot38(const float* __restrict__ w, const float* x) {
    float a0 = 0.f, a1 = 0.f;
    #pragma unroll
    for (int k = 0; k < 38; k += 2) {
        a0 = fmaf(x[k],   w[k],   a0);
        a1 = fmaf(x[k+1], w[k+1], a1);
    }
    return a0 + a1;
}

__global__ __launch_bounds__(64, 2) void symptom_v18(
    const float* __restrict__ x_g,
    const float* __restrict__ ipw, const float* __restrict__ ipb,
    const float* __restrict__ ow,  const float* __restrict__ ob,
    const float* __restrict__ l1w, const float* __restrict__ l1b,
    const float* __restrict__ l2w, const float* __restrict__ l2b,
    const float* __restrict__ ln1w, const float* __restrict__ ln1b,
    const float* __restrict__ ln2w, const float* __restrict__ ln2b,
    const float* __restrict__ attn_w, const float* __restrict__ attn_b,
    const float* __restrict__ clf_w,  const float* __restrict__ clf_b,
    float* __restrict__ out_logits,   // [B][8]
    float* __restrict__ out_scores)   // [B][8][64]
{
    const int b    = blockIdx.x;
    const int lane = threadIdx.x;     // row index (one wave per block)

    __shared__ __align__(16) float s_k[D*L];   // kT[d][m] 9728 B ; proj/t scratch overlay
    __shared__ __align__(16) float s_v[D*L];   // vT[d][m] 9728 B ; f scratch overlay
    // 19,456 B total -> 8 blocks/CU (2 waves/SIMD)

    // ---- stage x: coalesced global -> LDS (s_k as staging), then row -> regs ----
    const float* xb = x_g + (size_t)b*(L*D);
    for (int i = lane; i < L*D; i += 64) s_k[i] = xb[i];
    __syncthreads();
    float xr[D];
    #pragma unroll
    for (int k = 0; k < D; ++k) xr[k] = s_k[lane*D + k];
    __syncthreads();   // staging reads done before k overlay

    const float scale = 0.22941573387056174f;   // 1/sqrt(19)

    for (int layer = 0; layer < NL; ++layer) {
        const float* ipw_l = ipw + (size_t)layer*QKV*D;
        const float* ipb_l = ipb + layer*QKV;

        // ---- q (own row) into registers, unrolled ----
        float qreg[D];
        #pragma unroll
        for (int c = 0; c < D; ++c)
            qreg[c] = ipb_l[c] + dot38(ipw_l + c*D, xr);
        // ---- k, v -> LDS transposed (rolled) ----
        for (int cc = 0; cc < D; ++cc) {
            float kv = ipb_l[38+cc] + dot38(ipw_l + (38+cc)*D, xr);
            s_k[cc*L + lane] = kv;
            float vv = ipb_l[76+cc] + dot38(ipw_l + (76+cc)*D, xr);
            s_v[cc*L + lane] = vv;
        }
        __syncthreads();   // kT/vT ready (single-wave: waitcnt)

        // ---- attention: lane-local online softmax over 4 m-chunks ----
        float a[D];
        #pragma unroll
        for (int h = 0; h < 2; ++h) {
            float* ah = a + h*HD;
            #pragma unroll
            for (int d = 0; d < HD; ++d) ah[d] = 0.f;
            float M = -1e30f, S = 0.f;
            for (int mc = 0; mc < 4; ++mc) {     // rolled
                const int mb = mc*16;
                float p[16];
                #pragma unroll
                for (int j = 0; j < 16; ++j) p[j] = 0.f;
                #pragma unroll
                for (int d = 0; d < HD; ++d) {
                    const float* kp = s_k + (h*HD + d)*L + mb;   // wave-uniform
                    float4 k0 = *(const float4*)(kp);
                    float4 k1 = *(const float4*)(kp + 4);
                    float4 k2 = *(const float4*)(kp + 8);
                    float4 k3 = *(const float4*)(kp + 12);
                    float qd = qreg[h*HD + d];
                    p[0]=fmaf(k0.x,qd,p[0]); p[1]=fmaf(k0.y,qd,p[1]); p[2]=fmaf(k0.z,qd,p[2]); p[3]=fmaf(k0.w,qd,p[3]);
                    p[4]=fmaf(k1.x,qd,p[4]); p[5]=fmaf(k1.y,qd,p[5]); p[6]=fmaf(k1.z,qd,p[6]); p[7]=fmaf(k1.w,qd,p[7]);
                    p[8]=fmaf(k2.x,qd,p[8]); p[9]=fmaf(k2.y,qd,p[9]); p[10]=fmaf(k2.z,qd,p[10]); p[11]=fmaf(k2.w,qd,p[11]);
                    p[12]=fmaf(k3.x,qd,p[12]); p[13]=fmaf(k3.y,qd,p[13]); p[14]=fmaf(k3.z,qd,p[14]); p[15]=fmaf(k3.w,qd,p[15]);
                }
                #pragma unroll
                for (int j = 0; j < 16; ++j) p[j] *= scale;
                float mx = p[0];
                #pragma unroll
                for (int j = 1; j < 16; ++j) mx = fmaxf(mx, p[j]);
                float nM = fmaxf(M, mx);
                float r = __expf(M - nM);        // 0 on first chunk
                float cs = 0.f;
                #pragma unroll
                for (int j = 0; j < 16; ++j) { p[j] = __expf(p[j] - nM); cs += p[j]; }
                S = S*r + cs;
                #pragma unroll
                for (int d = 0; d < HD; ++d) {
                    const float* vp = s_v + (h*HD + d)*L + mb;   // wave-uniform
                    float4 v0 = *(const float4*)(vp);
                    float4 v1 = *(const float4*)(vp + 4);
                    float4 v2 = *(const float4*)(vp + 8);
                    float4 v3 = *(const float4*)(vp + 12);
                    float acc = 0.f;
                    acc=fmaf(v0.x,p[0],acc); acc=fmaf(v0.y,p[1],acc); acc=fmaf(v0.z,p[2],acc); acc=fmaf(v0.w,p[3],acc);
                    acc=fmaf(v1.x,p[4],acc); acc=fmaf(v1.y,p[5],acc); acc=fmaf(v1.z,p[6],acc); acc=fmaf(v1.w,p[7],acc);
                    acc=fmaf(v2.x,p[8],acc); acc=fmaf(v2.y,p[9],acc); acc=fmaf(v2.z,p[10],acc); acc=fmaf(v2.w,p[11],acc);
                    acc=fmaf(v3.x,p[12],acc); acc=fmaf(v3.y,p[13],acc); acc=fmaf(v3.z,p[14],acc); acc=fmaf(v3.w,p[15],acc);
                    ah[d] = ah[d]*r + acc;
                }
                M = nM;
            }
            float inv = 1.f/S;
            #pragma unroll
            for (int d = 0; d < HD; ++d) ah[d] *= inv;
        }
        __syncthreads();   // all kT/vT reads done -> scratch overlays legal

        // ---- out-proj (rolled -> s_k scratch) + residual + LN1 (lane-local) ----
        {
            const float* ow_l = ow + (size_t)layer*D*D;
            for (int c = 0; c < D; ++c)
                s_k[c*L + lane] = ob[layer*D + c] + dot38(ow_l + c*D, a);
            __syncthreads();
            float t[D]; float sum = 0.f, ssq = 0.f;
            #pragma unroll
            for (int c = 0; c < D; ++c) {
                t[c] = xr[c] + s_k[c*L + lane];
                sum += t[c]; ssq = fmaf(t[c], t[c], ssq);
            }
            float mu  = sum * (1.f/38.f);
            float var = ssq * (1.f/38.f) - mu*mu;
            float inv = rsqrtf(var + 1e-5f);
            #pragma unroll
            for (int c = 0; c < D; ++c)
                xr[c] = (t[c] - mu)*inv*ln1w[layer*D + c] + ln1b[layer*D + c];
        }

        // ---- FFN1 + exact GELU (rolled -> s_v scratch) ----
        {
            const float* l1w_l = l1w + (size_t)layer*D*D;
            for (int c = 0; c < D; ++c) {
                float g = l1b[layer*D + c] + dot38(l1w_l + c*D, xr);
                s_v[c*L + lane] = 0.5f*g*(1.0f + erff(g*0.70710678118654752f));
            }
            __syncthreads();
        }
        float fr[D];
        #pragma unroll
        for (int c = 0; c < D; ++c) fr[c] = s_v[c*L + lane];

        // ---- FFN2 (rolled -> s_k scratch) + residual + LN2 (lane-local) ----
        {
            const float* l2w_l = l2w + (size_t)layer*D*D;
            for (int c = 0; c < D; ++c)
                s_k[c*L + lane] = l2b[layer*D + c] + dot38(l2w_l + c*D, fr);
            __syncthreads();
            float t[D]; float sum = 0.f, ssq = 0.f;
            #pragma unroll
            for (int c = 0; c < D; ++c) {
                t[c] = xr[c] + s_k[c*L + lane];
                sum += t[c]; ssq = fmaf(t[c], t[c], ssq);
            }
            float mu  = sum * (1.f/38.f);
            float var = ssq * (1.f/38.f) - mu*mu;
            float inv = rsqrtf(var + 1e-5f);
            #pragma unroll
            for (int c = 0; c < D; ++c)
                xr[c] = (t[c] - mu)*inv*ln2w[layer*D + c] + ln2b[layer*D + c];
        }
        __syncthreads();   // scratch reads done before next layer's kT/vT writes
    }

    // ---- pooling + classifier (lane-local dots, wave-reduce softmax) ----
    #pragma unroll
    for (int k = 0; k < KD; ++k) {
        float sc = attn_b[k] + dot38(attn_w + k*D, xr);
        float mx = sc;
        #pragma unroll
        for (int off = 32; off > 0; off >>= 1) mx = fmaxf(mx, __shfl_xor(mx, off));
        float e = __expf(sc - mx);
        float sm = e;
        #pragma unroll
        for (int off = 32; off > 0; off >>= 1) sm += __shfl_xor(sm, off);
        float pr = e / sm;
        out_scores[(size_t)b*(KD*L) + k*L + lane] = pr;
        float y = dot38(clf_w + k*D, xr);
        float t = pr * y;
        #pragma unroll
        for (int off = 32; off > 0; off >>= 1) t += __shfl_xor(t, off);
        if (lane == 0) out_logits[(size_t)b*KD + k] = t + clf_b[k];
    }
}

extern "C" void kernel_launch(void* const* d_in, const int* in_sizes, int n_in,
                              void* d_out, int out_size, void* d_ws, size_t ws_size,
                              hipStream_t stream) {
    const float* x         = (const float*)d_in[0];
    const float* in_proj_w = (const float*)d_in[1];
    const float* in_proj_b = (const float*)d_in[2];
    const float* out_w     = (const float*)d_in[3];
    const float* out_b     = (const float*)d_in[4];
    const float* lin1_w    = (const float*)d_in[5];
    const float* lin1_b    = (const float*)d_in[6];
    const float* lin2_w    = (const float*)d_in[7];
    const float* lin2_b    = (const float*)d_in[8];
    const float* ln1_w     = (const float*)d_in[9];
    const float* ln1_b     = (const float*)d_in[10];
    const float* ln2_w     = (const float*)d_in[11];
    const float* ln2_b     = (const float*)d_in[12];
    const float* attn_w    = (const float*)d_in[13];
    const float* attn_b    = (const float*)d_in[14];
    const float* clf_w     = (const float*)d_in[15];
    const float* clf_b     = (const float*)d_in[16];

    const int B = in_sizes[0] / (L*D);             // 8192
    float* out_logits = (float*)d_out;             // [B][8]
    float* out_scores = out_logits + (size_t)B*KD; // [B][8][64]

    symptom_v18<<<B, 64, 0, stream>>>(
        x, in_proj_w, in_proj_b, out_w, out_b, lin1_w, lin1_b, lin2_w, lin2_b,
        ln1_w, ln1_b, ln2_w, ln2_b, attn_w, attn_b, clf_w, clf_b,
        out_logits, out_scores);
}